// Round 9
// baseline (295.558 us; speedup 1.0000x reference)
//
#include <hip/hip_runtime.h>
#include <hip/hip_bf16.h>
#include <cmath>
#include <cstdint>

// Problem dims (fixed by reference)
constexpr int B_ = 2, C_ = 96, H_ = 96, W_ = 96, L_ = H_ * W_;   // L = 9216
constexpr int N_ = 8, R_ = 6, K_ = 4, D_ = R_ + 2 * N_;          // D = 22
constexpr int CH_ = 128, G_ = L_ / CH_;                           // 72 chunks/sequence
constexpr int JS_ = 4, SEG_ = CH_ / JS_;                          // 4 sub-segments of 32
constexpr int S_ = G_ * JS_;                                      // 288 segments/sequence
constexpr float EPS_ = 1e-5f;

__device__ __forceinline__ float silu_f(float v) { return v / (1.f + __expf(-v)); }
__device__ __forceinline__ float softplus_f(float t) {
    return fmaxf(t, 0.f) + __logf(1.f + __expf(-fabsf(t)));
}

__device__ __forceinline__ void block_reduce2(float& a, float& b) {
    #pragma unroll
    for (int o = 32; o; o >>= 1) { a += __shfl_xor(a, o); b += __shfl_xor(b, o); }
    __shared__ float la[4], lb[4];
    int wid = threadIdx.x >> 6;
    if ((threadIdx.x & 63) == 0) { la[wid] = a; lb[wid] = b; }
    __syncthreads();
    if (threadIdx.x == 0) { a = la[0] + la[1] + la[2] + la[3]; b = lb[0] + lb[1] + lb[2] + lb[3]; }
}

__device__ __forceinline__ void block_reduce4(float& a, float& b, float& c, float& d) {
    #pragma unroll
    for (int o = 32; o; o >>= 1) {
        a += __shfl_xor(a, o); b += __shfl_xor(b, o);
        c += __shfl_xor(c, o); d += __shfl_xor(d, o);
    }
    __shared__ float ls[4][4];
    int wid = threadIdx.x >> 6;
    if ((threadIdx.x & 63) == 0) { ls[wid][0] = a; ls[wid][1] = b; ls[wid][2] = c; ls[wid][3] = d; }
    __syncthreads();
    if (threadIdx.x == 0) {
        a = ls[0][0] + ls[1][0] + ls[2][0] + ls[3][0];
        b = ls[0][1] + ls[1][1] + ls[2][1] + ls[3][1];
        c = ls[0][2] + ls[1][2] + ls[2][2] + ls[3][2];
        d = ls[0][3] + ls[1][3] + ls[2][3] + ls[3][3];
    }
}

// Fused: gn1 partial sums (blocks 0..431) + weight-fold prep (block 432) +
// xproj transpose (block 433): xpt[k][c][half*12+jj] = xproj[k][d][c].
__global__ __launch_bounds__(256) void stats_prep_kernel(
    const float* __restrict__ in, float* __restrict__ stats,
    const float* __restrict__ lng, const float* __restrict__ lnb,
    const float* __restrict__ w1, const float* __restrict__ w2,
    const float* __restrict__ xproj,
    float* __restrict__ wmt, float* __restrict__ pq, float* __restrict__ xpt) {
    if (blockIdx.x == 432) {
        if (blockIdx.y != 0) return;
        int t = threadIdx.x;
        if (t >= 192) return;
        int mat = t / 96, o = t % 96;
        const float* w = (mat == 0 ? w1 : w2) + o * C_;
        float* dst = wmt + ((size_t)(mat * 12 + o / 8) * C_) * 8 + (o % 8);
        float P = 0.f, Q = 0.f;
        for (int c = 0; c < C_; ++c) {
            float wv = w[c];
            float g = lng[c];
            P = fmaf(lnb[c], wv, P);
            Q = fmaf(g, wv, Q);
            dst[c * 8] = g * wv;
        }
        pq[mat * 192 + o] = P;
        pq[mat * 192 + 96 + o] = Q;
        return;
    }
    if (blockIdx.x == 433) {
        if (blockIdx.y != 0) return;
        for (int e = threadIdx.x; e < K_ * C_ * D_; e += 256) {
            int k = e / (C_ * D_);
            int rem = e % (C_ * D_);
            int c = rem / D_, d = rem % D_;
            int half = (d >= 11) ? 1 : 0;
            int jj = d - half * 11;
            xpt[((size_t)(k * C_ + c)) * 24 + half * 12 + jj] = xproj[(k * D_ + d) * C_ + c];
        }
        return;
    }
    int b = blockIdx.y;
    const float* p = in + (size_t)b * ((size_t)C_ * L_);
    float s = 0.f, s2 = 0.f;
    const int total = C_ * L_;
    for (int i = blockIdx.x * 256 + threadIdx.x; i < total; i += 432 * 256) {
        float v = p[i];
        s += v;
        s2 = fmaf(v, v, s2);
    }
    block_reduce2(s, s2);
    if (threadIdx.x == 0) {
        atomicAdd(&stats[2 * b], s);
        atomicAdd(&stats[2 * b + 1], s2);
    }
}

// Fused gn1 + both 1x1 convs via pre-folded weights (scalar broadcast loads).
__global__ __launch_bounds__(256) void conv1x1_kernel(
    const float* __restrict__ x, const float* __restrict__ stats,
    const float* __restrict__ wmt, const float* __restrict__ pq,
    const float* __restrict__ b1, const float* __restrict__ b2,
    float* __restrict__ a, float* __restrict__ bpre) {
    constexpr int OG = 8;
    int b = blockIdx.z, by = blockIdx.y;
    int o0 = by * OG;
    int l = blockIdx.x * 256 + threadIdx.x;

    constexpr float inv = 1.f / (float)(C_ * L_);
    float mu = stats[2 * b] * inv;
    float var = stats[2 * b + 1] * inv - mu * mu;
    float rs = rsqrtf(var + EPS_);

    const float4* w1q = (const float4*)(wmt + ((size_t)(0 * 12 + by) * C_) * 8);
    const float4* w2q = (const float4*)(wmt + ((size_t)(1 * 12 + by) * C_) * 8);

    const float* xb = x + (size_t)b * C_ * L_ + l;
    float acc1[OG], acc2[OG];
    #pragma unroll
    for (int j = 0; j < OG; ++j) { acc1[j] = 0.f; acc2[j] = 0.f; }
    #pragma unroll 4
    for (int c = 0; c < C_; ++c) {
        float xv = xb[(size_t)c * L_];
        float4 wa = w1q[2 * c];
        float4 wb = w1q[2 * c + 1];
        float4 wc = w2q[2 * c];
        float4 wd = w2q[2 * c + 1];
        acc1[0] = fmaf(xv, wa.x, acc1[0]); acc1[1] = fmaf(xv, wa.y, acc1[1]);
        acc1[2] = fmaf(xv, wa.z, acc1[2]); acc1[3] = fmaf(xv, wa.w, acc1[3]);
        acc1[4] = fmaf(xv, wb.x, acc1[4]); acc1[5] = fmaf(xv, wb.y, acc1[5]);
        acc1[6] = fmaf(xv, wb.z, acc1[6]); acc1[7] = fmaf(xv, wb.w, acc1[7]);
        acc2[0] = fmaf(xv, wc.x, acc2[0]); acc2[1] = fmaf(xv, wc.y, acc2[1]);
        acc2[2] = fmaf(xv, wc.z, acc2[2]); acc2[3] = fmaf(xv, wc.w, acc2[3]);
        acc2[4] = fmaf(xv, wd.x, acc2[4]); acc2[5] = fmaf(xv, wd.y, acc2[5]);
        acc2[6] = fmaf(xv, wd.z, acc2[6]); acc2[7] = fmaf(xv, wd.w, acc2[7]);
    }
    float murs = mu * rs;
    #pragma unroll
    for (int j = 0; j < OG; ++j) {
        int o = o0 + j;
        size_t oo = ((size_t)(b * C_ + o)) * L_ + l;
        float be1 = b1[o] + pq[o] - murs * pq[96 + o];
        float be2 = b2[o] + pq[192 + o] - murs * pq[288 + o];
        a[oo] = silu_f(fmaf(rs, acc1[j], be1));
        bpre[oo] = fmaf(rs, acc2[j], be2);
    }
}

// Fused depthwise 3x3 + bias + silu + transpose output (u and u_t).
__global__ __launch_bounds__(256) void dwt_kernel(const float* __restrict__ bp,
                                                  const float* __restrict__ wgt,
                                                  const float* __restrict__ bias,
                                                  float* __restrict__ u,
                                                  float* __restrict__ u_t) {
    int stripe = blockIdx.x, c = blockIdx.y, b = blockIdx.z;
    int h0 = stripe * 48;
    __shared__ float in_s[50][96];
    __shared__ float out_s[48][97];
    const float* in = bp + ((size_t)(b * C_ + c)) * L_;
    for (int idx = threadIdx.x; idx < 50 * 96; idx += 256) {
        int r = idx / 96, w = idx % 96;
        int hh = h0 - 1 + r;
        in_s[r][w] = (hh >= 0 && hh < 96) ? in[hh * 96 + w] : 0.f;
    }
    __syncthreads();
    const float* kw = wgt + c * 9;
    float k0 = kw[0], k1 = kw[1], k2 = kw[2], k3 = kw[3], k4 = kw[4],
          k5 = kw[5], k6 = kw[6], k7 = kw[7], k8 = kw[8];
    float bs = bias[c];
    float* up = u + ((size_t)(b * C_ + c)) * L_;
    for (int idx = threadIdx.x; idx < 48 * 96; idx += 256) {
        int r = idx / 96, w = idx % 96;
        int ri = r + 1;
        bool wl = (w > 0), wr = (w < 95);
        float acc = bs;
        acc = fmaf(wl ? in_s[ri - 1][w - 1] : 0.f, k0, acc);
        acc = fmaf(in_s[ri - 1][w], k1, acc);
        acc = fmaf(wr ? in_s[ri - 1][w + 1] : 0.f, k2, acc);
        acc = fmaf(wl ? in_s[ri][w - 1] : 0.f, k3, acc);
        acc = fmaf(in_s[ri][w], k4, acc);
        acc = fmaf(wr ? in_s[ri][w + 1] : 0.f, k5, acc);
        acc = fmaf(wl ? in_s[ri + 1][w - 1] : 0.f, k6, acc);
        acc = fmaf(in_s[ri + 1][w], k7, acc);
        acc = fmaf(wr ? in_s[ri + 1][w + 1] : 0.f, k8, acc);
        float v = silu_f(acc);
        up[(h0 + r) * 96 + w] = v;
        out_s[r][w] = v;
    }
    __syncthreads();
    float* tp = u_t + ((size_t)(b * C_ + c)) * L_;
    for (int idx = threadIdx.x; idx < 96 * 48; idx += 256) {
        int w = idx / 48, r = idx % 48;
        tp[w * 96 + h0 + r] = out_s[r][w];
    }
}

// Fused projection + phase-1 scan. Block = (g, k, b), 384 threads.
// Stages full 96x128 u tile; computes xdbl (22 outputs) in-block; writes
// dts/Bs/Cs once (for scan3); runs phase-1 scan for all 96 channels.
__global__ __launch_bounds__(384) void projscan1_kernel(
    const float* __restrict__ u, const float* __restrict__ u_t,
    const float* __restrict__ xpt, const float* __restrict__ dtw,
    const float* __restrict__ dtbv, const float* __restrict__ A_log,
    float* __restrict__ dts, float* __restrict__ Bsb, float* __restrict__ Csb,
    float* __restrict__ carA, float* __restrict__ carB) {
    int g = blockIdx.x, k = blockIdx.y, b = blockIdx.z;
    const int t = threadIdx.x;
    const int l0 = g * CH_;

    __shared__ float u_s[96][133];
    __shared__ float B_s[128][12];
    __shared__ float T_s[128][8];
    __shared__ float xp_s[96][24];

    // stage u tile (scan order; flip for k>=2)
    const float* usrc = ((k & 1) ? u_t : u) + (size_t)b * C_ * L_;
    if (k < 2) {
        for (int idx = t; idx < 96 * 32; idx += 384) {
            int c2 = idx >> 5, q = idx & 31;
            *(float4*)&u_s[c2][q * 4] = *(const float4*)(usrc + (size_t)c2 * L_ + l0 + q * 4);
        }
    } else {
        for (int idx = t; idx < 96 * 32; idx += 384) {
            int c2 = idx >> 5, q = idx & 31;
            float4 v = *(const float4*)(usrc + (size_t)c2 * L_ + (L_ - l0 - q * 4 - 4));
            u_s[c2][q * 4 + 0] = v.w; u_s[c2][q * 4 + 1] = v.z;
            u_s[c2][q * 4 + 2] = v.y; u_s[c2][q * 4 + 3] = v.x;
        }
    }
    // stage transposed xproj slice (96x24 contiguous)
    const float4* xsrc = (const float4*)(xpt + (size_t)k * C_ * 24);
    for (int idx = t; idx < 96 * 24 / 4; idx += 384) {
        ((float4*)xp_s)[idx] = xsrc[idx];
    }
    __syncthreads();

    // projection: threads 0..255 = (i, half); d = half*11 + j, j in [0,11)
    if (t < 256) {
        int i = t & 127, half = t >> 7;
        float acc[11];
        #pragma unroll
        for (int j = 0; j < 11; ++j) acc[j] = 0.f;
        const int hb = half * 12;
        for (int c = 0; c < C_; ++c) {
            float xv = u_s[c][i];
            float4 wa = *(const float4*)&xp_s[c][hb];
            float4 wb = *(const float4*)&xp_s[c][hb + 4];
            float4 wc = *(const float4*)&xp_s[c][hb + 8];
            acc[0] = fmaf(xv, wa.x, acc[0]); acc[1] = fmaf(xv, wa.y, acc[1]);
            acc[2] = fmaf(xv, wa.z, acc[2]); acc[3] = fmaf(xv, wa.w, acc[3]);
            acc[4] = fmaf(xv, wb.x, acc[4]); acc[5] = fmaf(xv, wb.y, acc[5]);
            acc[6] = fmaf(xv, wb.z, acc[6]); acc[7] = fmaf(xv, wb.w, acc[7]);
            acc[8] = fmaf(xv, wc.x, acc[8]); acc[9] = fmaf(xv, wc.y, acc[9]);
            acc[10] = fmaf(xv, wc.z, acc[10]);
        }
        int l = l0 + i;
        size_t bk = (size_t)(b * K_ + k);
        if (half == 0) {
            #pragma unroll
            for (int r = 0; r < R_; ++r) {
                dts[(bk * R_ + r) * L_ + l] = acc[r];
                T_s[i][r] = acc[r];
            }
            #pragma unroll
            for (int n = 0; n < 5; ++n) {
                Bsb[(bk * N_ + n) * L_ + l] = acc[6 + n];
                B_s[i][n] = acc[6 + n];
            }
        } else {
            #pragma unroll
            for (int n = 5; n < 8; ++n) {
                Bsb[(bk * N_ + n) * L_ + l] = acc[n - 5];
                B_s[i][n] = acc[n - 5];
            }
            #pragma unroll
            for (int n = 0; n < 8; ++n) {
                Csb[(bk * N_ + n) * L_ + l] = acc[3 + n];
            }
        }
    }
    __syncthreads();

    // phase-1 scan: 384 threads = 96 channels x 4 segments of 32
    int cc = t % 96, j = t / 96;
    int c = cc;
    float A[N_];
    #pragma unroll
    for (int n = 0; n < N_; ++n) A[n] = -__expf(A_log[(k * C_ + c) * N_ + n]);
    float wdt[R_];
    #pragma unroll
    for (int r = 0; r < R_; ++r) wdt[r] = dtw[(k * C_ + c) * R_ + r];
    float bdt = dtbv[k * C_ + c];

    float ap[N_], h[N_];
    #pragma unroll
    for (int n = 0; n < N_; ++n) { ap[n] = 1.f; h[n] = 0.f; }
    int i0 = j * SEG_;
    for (int ii = 0; ii < SEG_; ii += 4) {
        float4 x4 = *(float4*)&u_s[cc][i0 + ii];
        float xx[4] = {x4.x, x4.y, x4.z, x4.w};
        #pragma unroll
        for (int s = 0; s < 4; ++s) {
            int i = i0 + ii + s;
            float4 t4 = *(float4*)&T_s[i][0];
            float2 t2 = *(float2*)&T_s[i][4];
            float tt = bdt;
            tt = fmaf(t4.x, wdt[0], tt); tt = fmaf(t4.y, wdt[1], tt);
            tt = fmaf(t4.z, wdt[2], tt); tt = fmaf(t4.w, wdt[3], tt);
            tt = fmaf(t2.x, wdt[4], tt); tt = fmaf(t2.y, wdt[5], tt);
            float d = softplus_f(tt);
            float dx = d * xx[s];
            float4 ba = *(float4*)&B_s[i][0];
            float4 bb = *(float4*)&B_s[i][4];
            float bv[8] = {ba.x, ba.y, ba.z, ba.w, bb.x, bb.y, bb.z, bb.w};
            #pragma unroll
            for (int n = 0; n < N_; ++n) {
                float da = __expf(d * A[n]);
                ap[n] *= da;
                h[n] = fmaf(da, h[n], bv[n] * dx);
            }
        }
    }
    size_t sidx = (((size_t)((b * K_ + k) * C_ + c)) * S_ + (g * JS_ + j)) * N_;
    #pragma unroll
    for (int n = 0; n < N_; ++n) { carA[sidx + n] = ap[n]; carB[sidx + n] = h[n]; }
}

// Phase 2: serial composition over 288 segments per (b,k,c,n).
__global__ __launch_bounds__(256) void scan2_kernel(const float* __restrict__ carA,
                                                    const float* __restrict__ carB,
                                                    float* __restrict__ hinit) {
    int tid = blockIdx.x * 256 + threadIdx.x;
    if (tid >= B_ * K_ * C_ * N_) return;
    int n = tid & 7;
    size_t rowb = (size_t)(tid >> 3) * S_;
    float h = 0.f;
    for (int s = 0; s < S_; s += 8) {
        float av[8], bv[8];
        #pragma unroll
        for (int q = 0; q < 8; ++q) {
            size_t idx = (rowb + s + q) * N_ + n;
            av[q] = carA[idx]; bv[q] = carB[idx];
        }
        #pragma unroll
        for (int q = 0; q < 8; ++q) {
            size_t idx = (rowb + s + q) * N_ + n;
            hinit[idx] = h;
            h = fmaf(av[q], h, bv[q]);
        }
    }
}

// Phase 3: rescan with correct initial state; y -> ydir (scan order).
__global__ __launch_bounds__(192) void scan3_kernel(
    const float* __restrict__ dts, const float* __restrict__ dtw,
    const float* __restrict__ dtbv, const float* __restrict__ Bs,
    const float* __restrict__ Cs, const float* __restrict__ u,
    const float* __restrict__ u_t, const float* __restrict__ A_log,
    const float* __restrict__ Dsv, const float* __restrict__ hinit,
    float* __restrict__ ydir) {
    int g = blockIdx.x >> 1, chalf = blockIdx.x & 1;
    int k = blockIdx.y, b = blockIdx.z;
    int c0 = chalf * 48;
    const int t = threadIdx.x;
    const int l0 = g * CH_;

    __shared__ float u_s[48][133];
    __shared__ float B_s[128][12];
    __shared__ float C_s[128][12];
    __shared__ float T_s[128][8];

    const float* usrc = ((k & 1) ? u_t : u) + (size_t)b * C_ * L_ + (size_t)c0 * L_;
    if (k < 2) {
        for (int idx = t; idx < 48 * 32; idx += 192) {
            int c2 = idx >> 5, q = idx & 31;
            *(float4*)&u_s[c2][q * 4] = *(const float4*)(usrc + (size_t)c2 * L_ + l0 + q * 4);
        }
    } else {
        for (int idx = t; idx < 48 * 32; idx += 192) {
            int c2 = idx >> 5, q = idx & 31;
            float4 v = *(const float4*)(usrc + (size_t)c2 * L_ + (L_ - l0 - q * 4 - 4));
            u_s[c2][q * 4 + 0] = v.w; u_s[c2][q * 4 + 1] = v.z;
            u_s[c2][q * 4 + 2] = v.y; u_s[c2][q * 4 + 3] = v.x;
        }
    }
    const float* Bg = Bs + ((size_t)(b * K_ + k)) * N_ * L_ + l0;
    const float* Cg = Cs + ((size_t)(b * K_ + k)) * N_ * L_ + l0;
    for (int idx = t; idx < 8 * 32; idx += 192) {
        int n = idx >> 5, q = idx & 31;
        float4 v = *(const float4*)(Bg + (size_t)n * L_ + q * 4);
        B_s[q * 4 + 0][n] = v.x; B_s[q * 4 + 1][n] = v.y;
        B_s[q * 4 + 2][n] = v.z; B_s[q * 4 + 3][n] = v.w;
        float4 w = *(const float4*)(Cg + (size_t)n * L_ + q * 4);
        C_s[q * 4 + 0][n] = w.x; C_s[q * 4 + 1][n] = w.y;
        C_s[q * 4 + 2][n] = w.z; C_s[q * 4 + 3][n] = w.w;
    }
    const float* Tg = dts + ((size_t)(b * K_ + k)) * R_ * L_ + l0;
    for (int idx = t; idx < 6 * 32; idx += 192) {
        int r = idx >> 5, q = idx & 31;
        float4 v = *(const float4*)(Tg + (size_t)r * L_ + q * 4);
        T_s[q * 4 + 0][r] = v.x; T_s[q * 4 + 1][r] = v.y;
        T_s[q * 4 + 2][r] = v.z; T_s[q * 4 + 3][r] = v.w;
    }
    __syncthreads();

    int cc = t % 48, j = t / 48;
    int c = c0 + cc;
    float A[N_];
    #pragma unroll
    for (int n = 0; n < N_; ++n) A[n] = -__expf(A_log[(k * C_ + c) * N_ + n]);
    float wdt[R_];
    #pragma unroll
    for (int r = 0; r < R_; ++r) wdt[r] = dtw[(k * C_ + c) * R_ + r];
    float bdt = dtbv[k * C_ + c];
    float Dv = Dsv[k * C_ + c];

    float h[N_];
    size_t sidx = (((size_t)((b * K_ + k) * C_ + c)) * S_ + (g * JS_ + j)) * N_;
    #pragma unroll
    for (int n = 0; n < N_; ++n) h[n] = hinit[sidx + n];

    int i0 = j * SEG_;
    for (int ii = 0; ii < SEG_; ii += 4) {
        float4 x4 = *(float4*)&u_s[cc][i0 + ii];
        float xx[4] = {x4.x, x4.y, x4.z, x4.w};
        #pragma unroll
        for (int s = 0; s < 4; ++s) {
            int i = i0 + ii + s;
            float4 t4 = *(float4*)&T_s[i][0];
            float2 t2 = *(float2*)&T_s[i][4];
            float tt = bdt;
            tt = fmaf(t4.x, wdt[0], tt); tt = fmaf(t4.y, wdt[1], tt);
            tt = fmaf(t4.z, wdt[2], tt); tt = fmaf(t4.w, wdt[3], tt);
            tt = fmaf(t2.x, wdt[4], tt); tt = fmaf(t2.y, wdt[5], tt);
            float d = softplus_f(tt);
            float dx = d * xx[s];
            float4 ba = *(float4*)&B_s[i][0];
            float4 bb = *(float4*)&B_s[i][4];
            float4 ca = *(float4*)&C_s[i][0];
            float4 cb = *(float4*)&C_s[i][4];
            float bv[8] = {ba.x, ba.y, ba.z, ba.w, bb.x, bb.y, bb.z, bb.w};
            float cv[8] = {ca.x, ca.y, ca.z, ca.w, cb.x, cb.y, cb.z, cb.w};
            float y = Dv * xx[s];
            #pragma unroll
            for (int n = 0; n < N_; ++n) {
                float da = __expf(d * A[n]);
                h[n] = fmaf(da, h[n], bv[n] * dx);
                y = fmaf(cv[n], h[n], y);
            }
            u_s[cc][i] = y;
        }
    }
    __syncthreads();
    float* yg = ydir + ((size_t)((b * K_ + k) * C_ + c0)) * L_ + l0;
    for (int idx = t; idx < 48 * 32; idx += 192) {
        int c2 = idx >> 5, q = idx & 31;
        *(float4*)(yg + (size_t)c2 * L_ + q * 4) = *(float4*)&u_s[c2][q * 4];
    }
}

// Merge 4 direction planes -> ysum; accumulate gn2 stats + gating moments.
__global__ __launch_bounds__(256) void merge_kernel(const float* __restrict__ ydir,
                                                    const float* __restrict__ a,
                                                    float* __restrict__ ysum,
                                                    float* __restrict__ stats) {
    int h0 = blockIdx.x * 32;
    int c = blockIdx.y, b = blockIdx.z;
    __shared__ float t1[96][33], t3[96][33];
    const float* y0p = ydir + ((size_t)((b * K_ + 0) * C_ + c)) * L_;
    const float* y1p = ydir + ((size_t)((b * K_ + 1) * C_ + c)) * L_;
    const float* y2p = ydir + ((size_t)((b * K_ + 2) * C_ + c)) * L_;
    const float* y3p = ydir + ((size_t)((b * K_ + 3) * C_ + c)) * L_;
    for (int idx = threadIdx.x; idx < 96 * 32; idx += 256) {
        int w = idx >> 5, hh = idx & 31;
        t1[w][hh] = y1p[w * 96 + h0 + hh];
        t3[w][hh] = y3p[L_ - 1 - (w * 96 + h0 + hh)];
    }
    __syncthreads();
    float s = 0.f, s2 = 0.f, m0 = 0.f, m1 = 0.f;
    float* yout = ysum + ((size_t)(b * C_ + c)) * L_;
    const float* ap = a + ((size_t)(b * C_ + c)) * L_;
    for (int idx = threadIdx.x; idx < 32 * 96; idx += 256) {
        int hh = idx / 96, w = idx % 96;
        int pix = (h0 + hh) * 96 + w;
        float v = y0p[pix] + y2p[L_ - 1 - pix] + t1[w][hh] + t3[w][hh];
        float av = ap[pix];
        yout[pix] = v;
        s += v;
        s2 = fmaf(v, v, s2);
        m0 += av;
        m1 = fmaf(av, v, m1);
    }
    block_reduce4(s, s2, m0, m1);
    if (threadIdx.x == 0) {
        atomicAdd(&stats[4 + 2 * b], s);
        atomicAdd(&stats[5 + 2 * b], s2);
        atomicAdd(&stats[16 + b * C_ + c], m0);
        atomicAdd(&stats[256 + b * C_ + c], m1);
    }
}

// Final: per-block recompute of SE attention (tiny MLP) + gn2-apply + gate +
// attention scale + residual in one pass.
__global__ __launch_bounds__(256) void final_kernel(
    const float* __restrict__ x, const float* __restrict__ ysum,
    const float* __restrict__ a, const float* __restrict__ stats,
    const float* __restrict__ g2, const float* __restrict__ b2,
    const float* __restrict__ w1, const float* __restrict__ b1,
    const float* __restrict__ w2, const float* __restrict__ b2a,
    float* __restrict__ out) {
    int b = blockIdx.z, c = blockIdx.y;
    int pix = blockIdx.x * 256 + threadIdx.x;
    constexpr float inv = 1.f / (float)(C_ * L_);
    float mu = stats[4 + 2 * b] * inv;
    float var = stats[5 + 2 * b] * inv - mu * mu;
    float rs = rsqrtf(var + EPS_);

    __shared__ float zz[12];
    __shared__ float atv_s;
    int t = threadIdx.x;
    if (t < 12) {
        float acc = b1[t];
        for (int cc = 0; cc < C_; ++cc) {
            float M0 = stats[16 + b * C_ + cc];
            float M1 = stats[256 + b * C_ + cc];
            float ss = (g2[cc] * rs * (M1 - mu * M0) + b2[cc] * M0) * (1.f / (float)L_);
            acc = fmaf(w1[t * C_ + cc], ss, acc);
        }
        zz[t] = fmaxf(acc, 0.f);
    }
    __syncthreads();
    if (t == 0) {
        float acc = b2a[c];
        #pragma unroll
        for (int j = 0; j < 12; ++j) acc = fmaf(w2[c * 12 + j], zz[j], acc);
        atv_s = 1.f / (1.f + __expf(-acc));
    }
    __syncthreads();
    float at = atv_s;
    float gc = g2[c] * rs, bc = b2[c] - mu * rs * g2[c];
    size_t o = ((size_t)(b * C_ + c)) * L_ + pix;
    float bn = fmaf(ysum[o], gc, bc);
    out[o] = fmaf(a[o] * bn, at, x[o]);
}

extern "C" void kernel_launch(void* const* d_in, const int* in_sizes, int n_in,
                              void* d_out, int out_size, void* d_ws, size_t ws_size,
                              hipStream_t stream) {
    const float* x    = (const float*)d_in[0];
    const float* ln_g = (const float*)d_in[1];
    const float* ln_b = (const float*)d_in[2];
    const float* p1w  = (const float*)d_in[3];
    const float* p1b  = (const float*)d_in[4];
    const float* p2w  = (const float*)d_in[5];
    const float* p2b  = (const float*)d_in[6];
    const float* dww  = (const float*)d_in[7];
    const float* dwb  = (const float*)d_in[8];
    const float* xprj = (const float*)d_in[9];
    const float* dtw  = (const float*)d_in[10];
    const float* dtb  = (const float*)d_in[11];
    const float* Alog = (const float*)d_in[12];
    const float* Dsp  = (const float*)d_in[13];
    const float* n2g  = (const float*)d_in[14];
    const float* n2b  = (const float*)d_in[15];
    const float* caw1 = (const float*)d_in[16];
    const float* cab1 = (const float*)d_in[17];
    const float* caw2 = (const float*)d_in[18];
    const float* cab2 = (const float*)d_in[19];
    float* out = (float*)d_out;

    const size_t BCL = (size_t)B_ * C_ * L_ * sizeof(float);        // 7,077,888 B
    char* ws = (char*)d_ws;
    size_t off = 0;
    float* stats = (float*)(ws + off); off += 4096;
    float* wmt   = (float*)(ws + off); off += 2 * 12 * 96 * 8 * sizeof(float);
    float* pq    = (float*)(ws + off); off += 2 * 2 * 96 * sizeof(float);
    float* xpt   = (float*)(ws + off); off += (size_t)K_ * C_ * 24 * sizeof(float);
    float* a     = (float*)(ws + off); off += BCL;
    float* bpre  = (float*)(ws + off); off += BCL;      // carA overlays
    float* u     = (float*)(ws + off); off += BCL;      // ysum overlays after scan3
    float* u_t   = (float*)(ws + off); off += BCL;
    float* dts   = (float*)(ws + off); off += (size_t)B_ * K_ * R_ * L_ * sizeof(float);
    float* Bsb   = (float*)(ws + off); off += (size_t)B_ * K_ * N_ * L_ * sizeof(float);
    float* Csb   = (float*)(ws + off); off += (size_t)B_ * K_ * N_ * L_ * sizeof(float);
    float* carB  = (float*)(ws + off); off += (size_t)B_ * K_ * C_ * S_ * N_ * sizeof(float);
    float* hinit = (float*)(ws + off); off += (size_t)B_ * K_ * C_ * S_ * N_ * sizeof(float);
    float* ydir  = (float*)(ws + off); off += (size_t)B_ * K_ * C_ * L_ * sizeof(float);
    float* carA = bpre;   // bpre dead after dwt_kernel
    float* ysum = u;      // u dead after scan3

    hipMemsetAsync(stats, 0, 4096, stream);

    stats_prep_kernel<<<dim3(434, 2), 256, 0, stream>>>(x, stats, ln_g, ln_b,
                                                        p1w, p2w, xprj, wmt, pq, xpt);
    conv1x1_kernel<<<dim3(36, 12, 2), 256, 0, stream>>>(x, stats, wmt, pq, p1b, p2b, a, bpre);
    dwt_kernel<<<dim3(2, 96, 2), 256, 0, stream>>>(bpre, dww, dwb, u, u_t);
    projscan1_kernel<<<dim3(G_, K_, B_), 384, 0, stream>>>(u, u_t, xpt, dtw, dtb, Alog,
                                                           dts, Bsb, Csb, carA, carB);
    scan2_kernel<<<24, 256, 0, stream>>>(carA, carB, hinit);
    scan3_kernel<<<dim3(2 * G_, K_, B_), 192, 0, stream>>>(dts, dtw, dtb, Bsb, Csb, u, u_t,
                                                           Alog, Dsp, hinit, ydir);
    merge_kernel<<<dim3(3, 96, 2), 256, 0, stream>>>(ydir, a, ysum, stats);
    final_kernel<<<dim3(36, 96, 2), 256, 0, stream>>>(x, ysum, a, stats, n2g, n2b,
                                                      caw1, cab1, caw2, cab2, out);
}

// Round 10
// 269.889 us; speedup vs baseline: 1.0951x; 1.0951x over previous
//
#include <hip/hip_runtime.h>
#include <hip/hip_bf16.h>
#include <cmath>
#include <cstdint>

// Problem dims (fixed by reference)
constexpr int B_ = 2, C_ = 96, H_ = 96, W_ = 96, L_ = H_ * W_;   // L = 9216
constexpr int N_ = 8, R_ = 6, K_ = 4, D_ = R_ + 2 * N_;          // D = 22
constexpr int CH_ = 128, G_ = L_ / CH_;                           // 72 chunks/sequence
constexpr int JS_ = 4, SEG_ = CH_ / JS_;                          // 4 sub-segments of 32
constexpr int S_ = G_ * JS_;                                      // 288 segments/sequence
constexpr float EPS_ = 1e-5f;

__device__ __forceinline__ float silu_f(float v) { return v / (1.f + __expf(-v)); }
__device__ __forceinline__ float softplus_f(float t) {
    return fmaxf(t, 0.f) + __logf(1.f + __expf(-fabsf(t)));
}

__device__ __forceinline__ void block_reduce2(float& a, float& b) {
    #pragma unroll
    for (int o = 32; o; o >>= 1) { a += __shfl_xor(a, o); b += __shfl_xor(b, o); }
    __shared__ float la[4], lb[4];
    int wid = threadIdx.x >> 6;
    if ((threadIdx.x & 63) == 0) { la[wid] = a; lb[wid] = b; }
    __syncthreads();
    if (threadIdx.x == 0) { a = la[0] + la[1] + la[2] + la[3]; b = lb[0] + lb[1] + lb[2] + lb[3]; }
}

__device__ __forceinline__ void block_reduce4(float& a, float& b, float& c, float& d) {
    #pragma unroll
    for (int o = 32; o; o >>= 1) {
        a += __shfl_xor(a, o); b += __shfl_xor(b, o);
        c += __shfl_xor(c, o); d += __shfl_xor(d, o);
    }
    __shared__ float ls[4][4];
    int wid = threadIdx.x >> 6;
    if ((threadIdx.x & 63) == 0) { ls[wid][0] = a; ls[wid][1] = b; ls[wid][2] = c; ls[wid][3] = d; }
    __syncthreads();
    if (threadIdx.x == 0) {
        a = ls[0][0] + ls[1][0] + ls[2][0] + ls[3][0];
        b = ls[0][1] + ls[1][1] + ls[2][1] + ls[3][1];
        c = ls[0][2] + ls[1][2] + ls[2][2] + ls[3][2];
        d = ls[0][3] + ls[1][3] + ls[2][3] + ls[3][3];
    }
}

// Fused: gn1 partial sums (blocks 0..431) + weight-fold prep (block 432, y==0).
__global__ __launch_bounds__(256) void stats_prep_kernel(
    const float* __restrict__ in, float* __restrict__ stats,
    const float* __restrict__ lng, const float* __restrict__ lnb,
    const float* __restrict__ w1, const float* __restrict__ w2,
    float* __restrict__ wmt, float* __restrict__ pq) {
    if (blockIdx.x == 432) {
        if (blockIdx.y != 0) return;
        int t = threadIdx.x;                 // 192 used = 2 mats x 96 outputs
        if (t >= 192) return;
        int mat = t / 96, o = t % 96;
        const float* w = (mat == 0 ? w1 : w2) + o * C_;
        float* dst = wmt + ((size_t)(mat * 12 + o / 8) * C_) * 8 + (o % 8);
        float P = 0.f, Q = 0.f;
        for (int c = 0; c < C_; ++c) {
            float wv = w[c];
            float g = lng[c];
            P = fmaf(lnb[c], wv, P);
            Q = fmaf(g, wv, Q);
            dst[c * 8] = g * wv;
        }
        pq[mat * 192 + o] = P;
        pq[mat * 192 + 96 + o] = Q;
        return;
    }
    int b = blockIdx.y;
    const float* p = in + (size_t)b * ((size_t)C_ * L_);
    float s = 0.f, s2 = 0.f;
    const int total = C_ * L_;
    for (int i = blockIdx.x * 256 + threadIdx.x; i < total; i += 432 * 256) {
        float v = p[i];
        s += v;
        s2 = fmaf(v, v, s2);
    }
    block_reduce2(s, s2);
    if (threadIdx.x == 0) {
        atomicAdd(&stats[2 * b], s);
        atomicAdd(&stats[2 * b + 1], s2);
    }
}

// Fused gn1 + both 1x1 convs via pre-folded weights (scalar broadcast loads).
__global__ __launch_bounds__(256) void conv1x1_kernel(
    const float* __restrict__ x, const float* __restrict__ stats,
    const float* __restrict__ wmt, const float* __restrict__ pq,
    const float* __restrict__ b1, const float* __restrict__ b2,
    float* __restrict__ a, float* __restrict__ bpre) {
    constexpr int OG = 8;
    int b = blockIdx.z, by = blockIdx.y;
    int o0 = by * OG;
    int l = blockIdx.x * 256 + threadIdx.x;

    constexpr float inv = 1.f / (float)(C_ * L_);
    float mu = stats[2 * b] * inv;
    float var = stats[2 * b + 1] * inv - mu * mu;
    float rs = rsqrtf(var + EPS_);

    const float4* w1q = (const float4*)(wmt + ((size_t)(0 * 12 + by) * C_) * 8);
    const float4* w2q = (const float4*)(wmt + ((size_t)(1 * 12 + by) * C_) * 8);

    const float* xb = x + (size_t)b * C_ * L_ + l;
    float acc1[OG], acc2[OG];
    #pragma unroll
    for (int j = 0; j < OG; ++j) { acc1[j] = 0.f; acc2[j] = 0.f; }
    #pragma unroll 4
    for (int c = 0; c < C_; ++c) {
        float xv = xb[(size_t)c * L_];
        float4 wa = w1q[2 * c];
        float4 wb = w1q[2 * c + 1];
        float4 wc = w2q[2 * c];
        float4 wd = w2q[2 * c + 1];
        acc1[0] = fmaf(xv, wa.x, acc1[0]); acc1[1] = fmaf(xv, wa.y, acc1[1]);
        acc1[2] = fmaf(xv, wa.z, acc1[2]); acc1[3] = fmaf(xv, wa.w, acc1[3]);
        acc1[4] = fmaf(xv, wb.x, acc1[4]); acc1[5] = fmaf(xv, wb.y, acc1[5]);
        acc1[6] = fmaf(xv, wb.z, acc1[6]); acc1[7] = fmaf(xv, wb.w, acc1[7]);
        acc2[0] = fmaf(xv, wc.x, acc2[0]); acc2[1] = fmaf(xv, wc.y, acc2[1]);
        acc2[2] = fmaf(xv, wc.z, acc2[2]); acc2[3] = fmaf(xv, wc.w, acc2[3]);
        acc2[4] = fmaf(xv, wd.x, acc2[4]); acc2[5] = fmaf(xv, wd.y, acc2[5]);
        acc2[6] = fmaf(xv, wd.z, acc2[6]); acc2[7] = fmaf(xv, wd.w, acc2[7]);
    }
    float murs = mu * rs;
    #pragma unroll
    for (int j = 0; j < OG; ++j) {
        int o = o0 + j;
        size_t oo = ((size_t)(b * C_ + o)) * L_ + l;
        float be1 = b1[o] + pq[o] - murs * pq[96 + o];
        float be2 = b2[o] + pq[192 + o] - murs * pq[288 + o];
        a[oo] = silu_f(fmaf(rs, acc1[j], be1));
        bpre[oo] = fmaf(rs, acc2[j], be2);
    }
}

// Fused depthwise 3x3 + bias + silu + transpose output (u and u_t).
__global__ __launch_bounds__(256) void dwt_kernel(const float* __restrict__ bp,
                                                  const float* __restrict__ wgt,
                                                  const float* __restrict__ bias,
                                                  float* __restrict__ u,
                                                  float* __restrict__ u_t) {
    int stripe = blockIdx.x, c = blockIdx.y, b = blockIdx.z;
    int h0 = stripe * 48;
    __shared__ float in_s[50][96];
    __shared__ float out_s[48][97];
    const float* in = bp + ((size_t)(b * C_ + c)) * L_;
    for (int idx = threadIdx.x; idx < 50 * 96; idx += 256) {
        int r = idx / 96, w = idx % 96;
        int hh = h0 - 1 + r;
        in_s[r][w] = (hh >= 0 && hh < 96) ? in[hh * 96 + w] : 0.f;
    }
    __syncthreads();
    const float* kw = wgt + c * 9;
    float k0 = kw[0], k1 = kw[1], k2 = kw[2], k3 = kw[3], k4 = kw[4],
          k5 = kw[5], k6 = kw[6], k7 = kw[7], k8 = kw[8];
    float bs = bias[c];
    float* up = u + ((size_t)(b * C_ + c)) * L_;
    for (int idx = threadIdx.x; idx < 48 * 96; idx += 256) {
        int r = idx / 96, w = idx % 96;
        int ri = r + 1;
        bool wl = (w > 0), wr = (w < 95);
        float acc = bs;
        acc = fmaf(wl ? in_s[ri - 1][w - 1] : 0.f, k0, acc);
        acc = fmaf(in_s[ri - 1][w], k1, acc);
        acc = fmaf(wr ? in_s[ri - 1][w + 1] : 0.f, k2, acc);
        acc = fmaf(wl ? in_s[ri][w - 1] : 0.f, k3, acc);
        acc = fmaf(in_s[ri][w], k4, acc);
        acc = fmaf(wr ? in_s[ri][w + 1] : 0.f, k5, acc);
        acc = fmaf(wl ? in_s[ri + 1][w - 1] : 0.f, k6, acc);
        acc = fmaf(in_s[ri + 1][w], k7, acc);
        acc = fmaf(wr ? in_s[ri + 1][w + 1] : 0.f, k8, acc);
        float v = silu_f(acc);
        up[(h0 + r) * 96 + w] = v;
        out_s[r][w] = v;
    }
    __syncthreads();
    float* tp = u_t + ((size_t)(b * C_ + c)) * L_;
    for (int idx = threadIdx.x; idx < 96 * 48; idx += 256) {
        int w = idx / 48, r = idx % 48;
        tp[w * 96 + h0 + r] = out_s[r][w];
    }
}

// proj: c-split. Block = 256 thr = 64 positions x 4 c-groups (24 ch each).
__global__ __launch_bounds__(256) void proj_kernel(
    const float* __restrict__ u, const float* __restrict__ u_t,
    const float* __restrict__ xproj,
    float* __restrict__ dts, float* __restrict__ Bsb, float* __restrict__ Csb) {
    int b = blockIdx.z, k = blockIdx.y;
    int pos = threadIdx.x & 63, cg = threadIdx.x >> 6;
    int l = blockIdx.x * 64 + pos;

    __shared__ float sxp[C_][24];
    __shared__ float red[D_][4][64];
    for (int i = threadIdx.x; i < D_ * C_; i += 256) {
        int d = i / C_, c = i % C_;
        sxp[c][d] = xproj[(k * D_ + d) * C_ + c];
    }
    __syncthreads();

    const float* src = ((k & 1) ? u_t : u) + (size_t)b * C_ * L_;
    int posIdx = (k < 2) ? l : (L_ - 1 - l);
    const float* sp = src + (size_t)(cg * 24) * L_ + posIdx;

    float acc[D_];
    #pragma unroll
    for (int d = 0; d < D_; ++d) acc[d] = 0.f;
    #pragma unroll 4
    for (int ci = 0; ci < 24; ++ci) {
        int c = cg * 24 + ci;
        float xv = sp[(size_t)ci * L_];
        float w[22];
        *(float4*)&w[0]  = *(const float4*)&sxp[c][0];
        *(float4*)&w[4]  = *(const float4*)&sxp[c][4];
        *(float4*)&w[8]  = *(const float4*)&sxp[c][8];
        *(float4*)&w[12] = *(const float4*)&sxp[c][12];
        *(float4*)&w[16] = *(const float4*)&sxp[c][16];
        *(float2*)&w[20] = *(const float2*)&sxp[c][20];
        #pragma unroll
        for (int d = 0; d < D_; ++d) acc[d] = fmaf(xv, w[d], acc[d]);
    }
    #pragma unroll
    for (int d = 0; d < D_; ++d) red[d][cg][pos] = acc[d];
    __syncthreads();

    if (cg == 0) {
        #pragma unroll
        for (int r = 0; r < R_; ++r) {
            float s = red[r][0][pos] + red[r][1][pos] + red[r][2][pos] + red[r][3][pos];
            dts[((size_t)((b * K_ + k) * R_ + r)) * L_ + l] = s;
        }
    } else if (cg == 1) {
        #pragma unroll
        for (int n = 0; n < N_; ++n) {
            int d = R_ + n;
            float s = red[d][0][pos] + red[d][1][pos] + red[d][2][pos] + red[d][3][pos];
            Bsb[((size_t)((b * K_ + k) * N_ + n)) * L_ + l] = s;
        }
    } else if (cg == 2) {
        #pragma unroll
        for (int n = 0; n < N_; ++n) {
            int d = R_ + N_ + n;
            float s = red[d][0][pos] + red[d][1][pos] + red[d][2][pos] + red[d][3][pos];
            Csb[((size_t)((b * K_ + k) * N_ + n)) * L_ + l] = s;
        }
    }
}

// Phase 1: local scan from h=0, emit (prod dA, carry) per segment.
__global__ __launch_bounds__(192) void scan1_kernel(
    const float* __restrict__ dts, const float* __restrict__ dtw,
    const float* __restrict__ dtbv, const float* __restrict__ Bs,
    const float* __restrict__ u, const float* __restrict__ u_t,
    const float* __restrict__ A_log,
    float* __restrict__ carA, float* __restrict__ carB) {
    int g = blockIdx.x >> 1, chalf = blockIdx.x & 1;
    int k = blockIdx.y, b = blockIdx.z;
    int c0 = chalf * 48;
    const int t = threadIdx.x;
    const int l0 = g * CH_;

    __shared__ float u_s[48][133];
    __shared__ float B_s[128][12];
    __shared__ float T_s[128][8];

    const float* usrc = ((k & 1) ? u_t : u) + (size_t)b * C_ * L_ + (size_t)c0 * L_;
    if (k < 2) {
        for (int idx = t; idx < 48 * 32; idx += 192) {
            int c2 = idx >> 5, q = idx & 31;
            *(float4*)&u_s[c2][q * 4] = *(const float4*)(usrc + (size_t)c2 * L_ + l0 + q * 4);
        }
    } else {
        for (int idx = t; idx < 48 * 32; idx += 192) {
            int c2 = idx >> 5, q = idx & 31;
            float4 v = *(const float4*)(usrc + (size_t)c2 * L_ + (L_ - l0 - q * 4 - 4));
            u_s[c2][q * 4 + 0] = v.w; u_s[c2][q * 4 + 1] = v.z;
            u_s[c2][q * 4 + 2] = v.y; u_s[c2][q * 4 + 3] = v.x;
        }
    }
    const float* Bg = Bs + ((size_t)(b * K_ + k)) * N_ * L_ + l0;
    for (int idx = t; idx < 8 * 32; idx += 192) {
        int n = idx >> 5, q = idx & 31;
        float4 v = *(const float4*)(Bg + (size_t)n * L_ + q * 4);
        B_s[q * 4 + 0][n] = v.x; B_s[q * 4 + 1][n] = v.y;
        B_s[q * 4 + 2][n] = v.z; B_s[q * 4 + 3][n] = v.w;
    }
    const float* Tg = dts + ((size_t)(b * K_ + k)) * R_ * L_ + l0;
    for (int idx = t; idx < 6 * 32; idx += 192) {
        int r = idx >> 5, q = idx & 31;
        float4 v = *(const float4*)(Tg + (size_t)r * L_ + q * 4);
        T_s[q * 4 + 0][r] = v.x; T_s[q * 4 + 1][r] = v.y;
        T_s[q * 4 + 2][r] = v.z; T_s[q * 4 + 3][r] = v.w;
    }
    __syncthreads();

    int cc = t % 48, j = t / 48;
    int c = c0 + cc;
    float A[N_];
    #pragma unroll
    for (int n = 0; n < N_; ++n) A[n] = -__expf(A_log[(k * C_ + c) * N_ + n]);
    float wdt[R_];
    #pragma unroll
    for (int r = 0; r < R_; ++r) wdt[r] = dtw[(k * C_ + c) * R_ + r];
    float bdt = dtbv[k * C_ + c];

    float ap[N_], h[N_];
    #pragma unroll
    for (int n = 0; n < N_; ++n) { ap[n] = 1.f; h[n] = 0.f; }
    int i0 = j * SEG_;
    for (int ii = 0; ii < SEG_; ii += 4) {
        float4 x4 = *(float4*)&u_s[cc][i0 + ii];
        float xx[4] = {x4.x, x4.y, x4.z, x4.w};
        #pragma unroll
        for (int s = 0; s < 4; ++s) {
            int i = i0 + ii + s;
            float4 t4 = *(float4*)&T_s[i][0];
            float2 t2 = *(float2*)&T_s[i][4];
            float tt = bdt;
            tt = fmaf(t4.x, wdt[0], tt); tt = fmaf(t4.y, wdt[1], tt);
            tt = fmaf(t4.z, wdt[2], tt); tt = fmaf(t4.w, wdt[3], tt);
            tt = fmaf(t2.x, wdt[4], tt); tt = fmaf(t2.y, wdt[5], tt);
            float d = softplus_f(tt);
            float dx = d * xx[s];
            float4 ba = *(float4*)&B_s[i][0];
            float4 bb = *(float4*)&B_s[i][4];
            float bv[8] = {ba.x, ba.y, ba.z, ba.w, bb.x, bb.y, bb.z, bb.w};
            #pragma unroll
            for (int n = 0; n < N_; ++n) {
                float da = __expf(d * A[n]);
                ap[n] *= da;
                h[n] = fmaf(da, h[n], bv[n] * dx);
            }
        }
    }
    size_t sidx = (((size_t)((b * K_ + k) * C_ + c)) * S_ + (g * JS_ + j)) * N_;
    #pragma unroll
    for (int n = 0; n < N_; ++n) { carA[sidx + n] = ap[n]; carB[sidx + n] = h[n]; }
}

// Phase 2 (parallel): block per (b,k,c) row. LDS-staged hierarchical scan:
// 256 thr = 8 n x 32 groups of 9 segments; shfl-scan composes groups.
__global__ __launch_bounds__(256) void scan2_kernel(const float* __restrict__ carA,
                                                    const float* __restrict__ carB,
                                                    float* __restrict__ hinit) {
    int row = blockIdx.x;              // (b*K + k)*C + c  (768 rows)
    const int t = threadIdx.x;
    __shared__ float as_[S_ * N_];     // 2304 floats
    __shared__ float bs_[S_ * N_];
    const float4* Ag = (const float4*)(carA + (size_t)row * S_ * N_);
    const float4* Bg4 = (const float4*)(carB + (size_t)row * S_ * N_);
    float4* As4 = (float4*)as_;
    float4* Bs4 = (float4*)bs_;
    for (int i = t; i < S_ * N_ / 4; i += 256) { As4[i] = Ag[i]; Bs4[i] = Bg4[i]; }
    __syncthreads();

    int n = t >> 5, g = t & 31;        // group g covers segments g*9 .. g*9+8
    int s0 = g * 9;
    float A = 1.f, Bc = 0.f;
    #pragma unroll
    for (int q = 0; q < 9; ++q) {
        int idx = (s0 + q) * N_ + n;
        float a = as_[idx], b = bs_[idx];
        Bc = fmaf(a, Bc, b);
        A = a * A;
    }
    // inclusive affine-compose scan across 32 groups (width-32 shfl)
    #pragma unroll
    for (int d = 1; d < 32; d <<= 1) {
        float pA = __shfl_up(A, d, 32);
        float pB = __shfl_up(Bc, d, 32);
        if (g >= d) { Bc = fmaf(A, pB, Bc); A = A * pA; }
    }
    float h = __shfl_up(Bc, 1, 32);
    if (g == 0) h = 0.f;
    // rescan 9 segments, writing hinit values into as_ (each idx read once first)
    #pragma unroll
    for (int q = 0; q < 9; ++q) {
        int idx = (s0 + q) * N_ + n;
        float a = as_[idx], b = bs_[idx];
        as_[idx] = h;
        h = fmaf(a, h, b);
    }
    __syncthreads();
    float4* Hg = (float4*)(hinit + (size_t)row * S_ * N_);
    for (int i = t; i < S_ * N_ / 4; i += 256) Hg[i] = As4[i];
}

// Phase 3: rescan with correct initial state; y -> ydir (scan order).
__global__ __launch_bounds__(192) void scan3_kernel(
    const float* __restrict__ dts, const float* __restrict__ dtw,
    const float* __restrict__ dtbv, const float* __restrict__ Bs,
    const float* __restrict__ Cs, const float* __restrict__ u,
    const float* __restrict__ u_t, const float* __restrict__ A_log,
    const float* __restrict__ Dsv, const float* __restrict__ hinit,
    float* __restrict__ ydir) {
    int g = blockIdx.x >> 1, chalf = blockIdx.x & 1;
    int k = blockIdx.y, b = blockIdx.z;
    int c0 = chalf * 48;
    const int t = threadIdx.x;
    const int l0 = g * CH_;

    __shared__ float u_s[48][133];
    __shared__ float B_s[128][12];
    __shared__ float C_s[128][12];
    __shared__ float T_s[128][8];

    const float* usrc = ((k & 1) ? u_t : u) + (size_t)b * C_ * L_ + (size_t)c0 * L_;
    if (k < 2) {
        for (int idx = t; idx < 48 * 32; idx += 192) {
            int c2 = idx >> 5, q = idx & 31;
            *(float4*)&u_s[c2][q * 4] = *(const float4*)(usrc + (size_t)c2 * L_ + l0 + q * 4);
        }
    } else {
        for (int idx = t; idx < 48 * 32; idx += 192) {
            int c2 = idx >> 5, q = idx & 31;
            float4 v = *(const float4*)(usrc + (size_t)c2 * L_ + (L_ - l0 - q * 4 - 4));
            u_s[c2][q * 4 + 0] = v.w; u_s[c2][q * 4 + 1] = v.z;
            u_s[c2][q * 4 + 2] = v.y; u_s[c2][q * 4 + 3] = v.x;
        }
    }
    const float* Bg = Bs + ((size_t)(b * K_ + k)) * N_ * L_ + l0;
    const float* Cg = Cs + ((size_t)(b * K_ + k)) * N_ * L_ + l0;
    for (int idx = t; idx < 8 * 32; idx += 192) {
        int n = idx >> 5, q = idx & 31;
        float4 v = *(const float4*)(Bg + (size_t)n * L_ + q * 4);
        B_s[q * 4 + 0][n] = v.x; B_s[q * 4 + 1][n] = v.y;
        B_s[q * 4 + 2][n] = v.z; B_s[q * 4 + 3][n] = v.w;
        float4 w = *(const float4*)(Cg + (size_t)n * L_ + q * 4);
        C_s[q * 4 + 0][n] = w.x; C_s[q * 4 + 1][n] = w.y;
        C_s[q * 4 + 2][n] = w.z; C_s[q * 4 + 3][n] = w.w;
    }
    const float* Tg = dts + ((size_t)(b * K_ + k)) * R_ * L_ + l0;
    for (int idx = t; idx < 6 * 32; idx += 192) {
        int r = idx >> 5, q = idx & 31;
        float4 v = *(const float4*)(Tg + (size_t)r * L_ + q * 4);
        T_s[q * 4 + 0][r] = v.x; T_s[q * 4 + 1][r] = v.y;
        T_s[q * 4 + 2][r] = v.z; T_s[q * 4 + 3][r] = v.w;
    }
    __syncthreads();

    int cc = t % 48, j = t / 48;
    int c = c0 + cc;
    float A[N_];
    #pragma unroll
    for (int n = 0; n < N_; ++n) A[n] = -__expf(A_log[(k * C_ + c) * N_ + n]);
    float wdt[R_];
    #pragma unroll
    for (int r = 0; r < R_; ++r) wdt[r] = dtw[(k * C_ + c) * R_ + r];
    float bdt = dtbv[k * C_ + c];
    float Dv = Dsv[k * C_ + c];

    float h[N_];
    size_t sidx = (((size_t)((b * K_ + k) * C_ + c)) * S_ + (g * JS_ + j)) * N_;
    #pragma unroll
    for (int n = 0; n < N_; ++n) h[n] = hinit[sidx + n];

    int i0 = j * SEG_;
    for (int ii = 0; ii < SEG_; ii += 4) {
        float4 x4 = *(float4*)&u_s[cc][i0 + ii];
        float xx[4] = {x4.x, x4.y, x4.z, x4.w};
        #pragma unroll
        for (int s = 0; s < 4; ++s) {
            int i = i0 + ii + s;
            float4 t4 = *(float4*)&T_s[i][0];
            float2 t2 = *(float2*)&T_s[i][4];
            float tt = bdt;
            tt = fmaf(t4.x, wdt[0], tt); tt = fmaf(t4.y, wdt[1], tt);
            tt = fmaf(t4.z, wdt[2], tt); tt = fmaf(t4.w, wdt[3], tt);
            tt = fmaf(t2.x, wdt[4], tt); tt = fmaf(t2.y, wdt[5], tt);
            float d = softplus_f(tt);
            float dx = d * xx[s];
            float4 ba = *(float4*)&B_s[i][0];
            float4 bb = *(float4*)&B_s[i][4];
            float4 ca = *(float4*)&C_s[i][0];
            float4 cb = *(float4*)&C_s[i][4];
            float bv[8] = {ba.x, ba.y, ba.z, ba.w, bb.x, bb.y, bb.z, bb.w};
            float cv[8] = {ca.x, ca.y, ca.z, ca.w, cb.x, cb.y, cb.z, cb.w};
            float y = Dv * xx[s];
            #pragma unroll
            for (int n = 0; n < N_; ++n) {
                float da = __expf(d * A[n]);
                h[n] = fmaf(da, h[n], bv[n] * dx);
                y = fmaf(cv[n], h[n], y);
            }
            u_s[cc][i] = y;
        }
    }
    __syncthreads();
    float* yg = ydir + ((size_t)((b * K_ + k) * C_ + c0)) * L_ + l0;
    for (int idx = t; idx < 48 * 32; idx += 192) {
        int c2 = idx >> 5, q = idx & 31;
        *(float4*)(yg + (size_t)c2 * L_ + q * 4) = *(float4*)&u_s[c2][q * 4];
    }
}

// Merge 4 direction planes -> ysum; accumulate gn2 stats + gating moments.
__global__ __launch_bounds__(256) void merge_kernel(const float* __restrict__ ydir,
                                                    const float* __restrict__ a,
                                                    float* __restrict__ ysum,
                                                    float* __restrict__ stats) {
    int h0 = blockIdx.x * 32;
    int c = blockIdx.y, b = blockIdx.z;
    __shared__ float t1[96][33], t3[96][33];
    const float* y0p = ydir + ((size_t)((b * K_ + 0) * C_ + c)) * L_;
    const float* y1p = ydir + ((size_t)((b * K_ + 1) * C_ + c)) * L_;
    const float* y2p = ydir + ((size_t)((b * K_ + 2) * C_ + c)) * L_;
    const float* y3p = ydir + ((size_t)((b * K_ + 3) * C_ + c)) * L_;
    for (int idx = threadIdx.x; idx < 96 * 32; idx += 256) {
        int w = idx >> 5, hh = idx & 31;
        t1[w][hh] = y1p[w * 96 + h0 + hh];
        t3[w][hh] = y3p[L_ - 1 - (w * 96 + h0 + hh)];
    }
    __syncthreads();
    float s = 0.f, s2 = 0.f, m0 = 0.f, m1 = 0.f;
    float* yout = ysum + ((size_t)(b * C_ + c)) * L_;
    const float* ap = a + ((size_t)(b * C_ + c)) * L_;
    for (int idx = threadIdx.x; idx < 32 * 96; idx += 256) {
        int hh = idx / 96, w = idx % 96;
        int pix = (h0 + hh) * 96 + w;
        float v = y0p[pix] + y2p[L_ - 1 - pix] + t1[w][hh] + t3[w][hh];
        float av = ap[pix];
        yout[pix] = v;
        s += v;
        s2 = fmaf(v, v, s2);
        m0 += av;
        m1 = fmaf(av, v, m1);
    }
    block_reduce4(s, s2, m0, m1);
    if (threadIdx.x == 0) {
        atomicAdd(&stats[4 + 2 * b], s);
        atomicAdd(&stats[5 + 2 * b], s2);
        atomicAdd(&stats[16 + b * C_ + c], m0);
        atomicAdd(&stats[256 + b * C_ + c], m1);
    }
}

// SE attention from moments.
__global__ __launch_bounds__(128) void attn_kernel(
    const float* __restrict__ stats, const float* __restrict__ g2,
    const float* __restrict__ b2, const float* __restrict__ w1,
    const float* __restrict__ b1, const float* __restrict__ w2,
    const float* __restrict__ b2a, float* __restrict__ attn) {
    int b = blockIdx.x;
    constexpr float inv = 1.f / (float)(C_ * L_);
    float mu = stats[4 + 2 * b] * inv;
    float var = stats[5 + 2 * b] * inv - mu * mu;
    float rs = rsqrtf(var + EPS_);
    __shared__ float ss[C_];
    __shared__ float zz[12];
    int t = threadIdx.x;
    if (t < C_) {
        float M0 = stats[16 + b * C_ + t];
        float M1 = stats[256 + b * C_ + t];
        ss[t] = (g2[t] * rs * (M1 - mu * M0) + b2[t] * M0) * (1.f / (float)L_);
    }
    __syncthreads();
    if (t < 12) {
        float acc = b1[t];
        for (int c = 0; c < C_; ++c) acc = fmaf(w1[t * C_ + c], ss[c], acc);
        zz[t] = fmaxf(acc, 0.f);
    }
    __syncthreads();
    if (t < C_) {
        float acc = b2a[t];
        #pragma unroll
        for (int j = 0; j < 12; ++j) acc = fmaf(w2[t * 12 + j], zz[j], acc);
        attn[b * C_ + t] = 1.f / (1.f + __expf(-acc));
    }
}

// Final: gn2-apply + gate + attention scale + residual in one pass.
__global__ __launch_bounds__(256) void final_kernel(const float* __restrict__ x,
                                                    const float* __restrict__ ysum,
                                                    const float* __restrict__ a,
                                                    const float* __restrict__ stats,
                                                    const float* __restrict__ g2,
                                                    const float* __restrict__ b2,
                                                    const float* __restrict__ attn,
                                                    float* __restrict__ out) {
    int b = blockIdx.z, c = blockIdx.y;
    int pix = blockIdx.x * 256 + threadIdx.x;
    constexpr float inv = 1.f / (float)(C_ * L_);
    float mu = stats[4 + 2 * b] * inv;
    float var = stats[5 + 2 * b] * inv - mu * mu;
    float rs = rsqrtf(var + EPS_);
    float gc = g2[c] * rs, bc = b2[c] - mu * rs * g2[c];
    float at = attn[b * C_ + c];
    size_t o = ((size_t)(b * C_ + c)) * L_ + pix;
    float bn = fmaf(ysum[o], gc, bc);
    out[o] = fmaf(a[o] * bn, at, x[o]);
}

extern "C" void kernel_launch(void* const* d_in, const int* in_sizes, int n_in,
                              void* d_out, int out_size, void* d_ws, size_t ws_size,
                              hipStream_t stream) {
    const float* x    = (const float*)d_in[0];
    const float* ln_g = (const float*)d_in[1];
    const float* ln_b = (const float*)d_in[2];
    const float* p1w  = (const float*)d_in[3];
    const float* p1b  = (const float*)d_in[4];
    const float* p2w  = (const float*)d_in[5];
    const float* p2b  = (const float*)d_in[6];
    const float* dww  = (const float*)d_in[7];
    const float* dwb  = (const float*)d_in[8];
    const float* xprj = (const float*)d_in[9];
    const float* dtw  = (const float*)d_in[10];
    const float* dtb  = (const float*)d_in[11];
    const float* Alog = (const float*)d_in[12];
    const float* Dsp  = (const float*)d_in[13];
    const float* n2g  = (const float*)d_in[14];
    const float* n2b  = (const float*)d_in[15];
    const float* caw1 = (const float*)d_in[16];
    const float* cab1 = (const float*)d_in[17];
    const float* caw2 = (const float*)d_in[18];
    const float* cab2 = (const float*)d_in[19];
    float* out = (float*)d_out;

    const size_t BCL = (size_t)B_ * C_ * L_ * sizeof(float);        // 7,077,888 B
    char* ws = (char*)d_ws;
    size_t off = 0;
    float* stats = (float*)(ws + off); off += 4096;
    float* wmt   = (float*)(ws + off); off += 2 * 12 * 96 * 8 * sizeof(float);
    float* pq    = (float*)(ws + off); off += 2 * 2 * 96 * sizeof(float);
    float* a     = (float*)(ws + off); off += BCL;
    float* bpre  = (float*)(ws + off); off += BCL;      // carA overlays
    float* u     = (float*)(ws + off); off += BCL;      // ysum overlays after scan3
    float* u_t   = (float*)(ws + off); off += BCL;
    float* dts   = (float*)(ws + off); off += (size_t)B_ * K_ * R_ * L_ * sizeof(float);
    float* Bsb   = (float*)(ws + off); off += (size_t)B_ * K_ * N_ * L_ * sizeof(float);
    float* Csb   = (float*)(ws + off); off += (size_t)B_ * K_ * N_ * L_ * sizeof(float);
    float* carB  = (float*)(ws + off); off += (size_t)B_ * K_ * C_ * S_ * N_ * sizeof(float);
    float* hinit = (float*)(ws + off); off += (size_t)B_ * K_ * C_ * S_ * N_ * sizeof(float);
    float* ydir  = (float*)(ws + off); off += (size_t)B_ * K_ * C_ * L_ * sizeof(float);
    float* carA = bpre;   // bpre dead after dwt_kernel
    float* ysum = u;      // u dead after scan3
    float* attnv = stats + 512;

    hipMemsetAsync(stats, 0, 4096, stream);

    stats_prep_kernel<<<dim3(433, 2), 256, 0, stream>>>(x, stats, ln_g, ln_b,
                                                        p1w, p2w, wmt, pq);
    conv1x1_kernel<<<dim3(36, 12, 2), 256, 0, stream>>>(x, stats, wmt, pq, p1b, p2b, a, bpre);
    dwt_kernel<<<dim3(2, 96, 2), 256, 0, stream>>>(bpre, dww, dwb, u, u_t);
    proj_kernel<<<dim3(144, 4, 2), 256, 0, stream>>>(u, u_t, xprj, dts, Bsb, Csb);
    scan1_kernel<<<dim3(2 * G_, K_, B_), 192, 0, stream>>>(dts, dtw, dtb, Bsb, u, u_t,
                                                           Alog, carA, carB);
    scan2_kernel<<<B_ * K_ * C_, 256, 0, stream>>>(carA, carB, hinit);
    scan3_kernel<<<dim3(2 * G_, K_, B_), 192, 0, stream>>>(dts, dtw, dtb, Bsb, Csb, u, u_t,
                                                           Alog, Dsp, hinit, ydir);
    merge_kernel<<<dim3(3, 96, 2), 256, 0, stream>>>(ydir, a, ysum, stats);
    attn_kernel<<<2, 128, 0, stream>>>(stats, n2g, n2b, caw1, cab1, caw2, cab2, attnv);
    final_kernel<<<dim3(36, 96, 2), 256, 0, stream>>>(x, ysum, a, stats, n2g, n2b, attnv, out);
}